// Round 1
// baseline (241.143 us; speedup 1.0000x reference)
//
#include <hip/hip_runtime.h>

// ButterflyLinear: N=4096, DEPTH=12, TOKENS=8192, all fp32.
// Key structural fact: stage 0 pairs (2p,2p+1); every stage>=1 pairs
// (pos, pos+2) inside aligned 4-groups. So each aligned float4 group of a
// row is closed under ALL stages -> whole 12-stage chain runs per-thread
// in registers. Factor indices depend only on the group index k, so the
// 24 factors are preloaded once per thread and reused across tokens.

#define NFEAT   4096
#define DEPTH   12
#define NPAIR   (NFEAT / 2)      // 2048 factor rows per stage
#define NGROUPS (NFEAT / 4)      // 1024 float4 groups per token
#define GBLK    256              // threads per block = groups per block
#define TOK_PER_BLK 16
#define TOKENS  8192

__global__ __launch_bounds__(GBLK)
void butterfly_kernel(const float* __restrict__ x,
                      const float* __restrict__ factors,
                      const float* __restrict__ bias,
                      float* __restrict__ out)
{
    const int k    = blockIdx.x * GBLK + threadIdx.x;  // group index 0..1023
    const int tok0 = blockIdx.y * TOK_PER_BLK;

    // ---- preload per-group factors into registers (fully static indexing) ----
    float4 f[DEPTH][2];
    f[0][0] = *(const float4*)(factors + (size_t)(0 * NPAIR + 2 * k    ) * 4);
    f[0][1] = *(const float4*)(factors + (size_t)(0 * NPAIR + 2 * k + 1) * 4);
#pragma unroll
    for (int s = 1; s < DEPTH; ++s) {
        const int lowmask = (1 << (s - 1)) - 1;
        const int p0 = ((k >> (s - 1)) << s) | (k & lowmask);
        const int p1 = p0 + (1 << (s - 1));
        f[s][0] = *(const float4*)(factors + (size_t)(s * NPAIR + p0) * 4);
        f[s][1] = *(const float4*)(factors + (size_t)(s * NPAIR + p1) * 4);
    }
    const float4 bv = *(const float4*)(bias + 4 * k);

    // ---- stream tokens: load float4, 12 stages in regs, +bias, store ----
    for (int t = 0; t < TOK_PER_BLK; ++t) {
        const int b = tok0 + t;
        float4 v = *(const float4*)(x + (size_t)b * NFEAT + 4 * k);

        // stage 0: pairs (v0,v1) w/ f[0][0], (v2,v3) w/ f[0][1]
        {
            const float n0 = v.x * f[0][0].x + v.y * f[0][0].z;
            const float n1 = v.x * f[0][0].y + v.y * f[0][0].w;
            const float n2 = v.z * f[0][1].x + v.w * f[0][1].z;
            const float n3 = v.z * f[0][1].y + v.w * f[0][1].w;
            v = make_float4(n0, n1, n2, n3);
        }
        // stages 1..11: pairs (v0,v2) w/ f[s][0], (v1,v3) w/ f[s][1]
#pragma unroll
        for (int s = 1; s < DEPTH; ++s) {
            const float n0 = v.x * f[s][0].x + v.z * f[s][0].z;
            const float n2 = v.x * f[s][0].y + v.z * f[s][0].w;
            const float n1 = v.y * f[s][1].x + v.w * f[s][1].z;
            const float n3 = v.y * f[s][1].y + v.w * f[s][1].w;
            v = make_float4(n0, n1, n2, n3);
        }

        v.x += bv.x; v.y += bv.y; v.z += bv.z; v.w += bv.w;
        *(float4*)(out + (size_t)b * NFEAT + 4 * k) = v;
    }
}

extern "C" void kernel_launch(void* const* d_in, const int* in_sizes, int n_in,
                              void* d_out, int out_size, void* d_ws, size_t ws_size,
                              hipStream_t stream) {
    const float* x       = (const float*)d_in[0];
    const float* factors = (const float*)d_in[1];
    const float* bias    = (const float*)d_in[2];
    float* out           = (float*)d_out;

    dim3 grid(NGROUPS / GBLK, TOKENS / TOK_PER_BLK);  // (4, 512) = 2048 blocks
    dim3 block(GBLK);
    butterfly_kernel<<<grid, block, 0, stream>>>(x, factors, bias, out);
}

// Round 3
// 228.456 us; speedup vs baseline: 1.0555x; 1.0555x over previous
//
#include <hip/hip_runtime.h>

// ButterflyLinear: N=4096, DEPTH=12, TOKENS=8192, fp32.
// All 12 stages act within aligned float4 groups (verified R0: passed).
// R1/R2: per-group 12-stage chain == constant 4x4 linear map M_k.
//   Kernel 1 (tiny): compose M_k for the 1024 groups -> d_ws (64 KB).
//   Kernel 2 (stream): out = M_k * x + bias. 1 ld + 16 FMA + 1 st per token.

#define NFEAT   4096
#define DEPTH   12
#define NPAIR   (NFEAT / 2)
#define NGROUPS (NFEAT / 4)      // 1024
#define TOKENS  8192
#define GBLK    256
#define TOK_PER_BLK 8

typedef float fx4 __attribute__((ext_vector_type(4)));  // native vec for NT builtins

__device__ __forceinline__ float4 stage0_apply(float4 v, float4 a, float4 b) {
    return make_float4(v.x * a.x + v.y * a.z,
                       v.x * a.y + v.y * a.w,
                       v.z * b.x + v.w * b.z,
                       v.z * b.y + v.w * b.w);
}
__device__ __forceinline__ float4 stageS_apply(float4 v, float4 a, float4 b) {
    // pairs (v0,v2) w/ a, (v1,v3) w/ b
    return make_float4(v.x * a.x + v.z * a.z,
                       v.y * b.x + v.w * b.z,
                       v.x * a.y + v.z * a.w,
                       v.y * b.y + v.w * b.w);
}

// ---- kernel 1: compose the 4x4 map per group, stored as 4 column vectors ----
__global__ __launch_bounds__(256)
void compose_kernel(const float* __restrict__ factors, float* __restrict__ M)
{
    const int k = blockIdx.x * 256 + threadIdx.x;   // group 0..1023

    float4 c0 = make_float4(1.f, 0.f, 0.f, 0.f);
    float4 c1 = make_float4(0.f, 1.f, 0.f, 0.f);
    float4 c2 = make_float4(0.f, 0.f, 1.f, 0.f);
    float4 c3 = make_float4(0.f, 0.f, 0.f, 1.f);

    {   // stage 0: factors 2k, 2k+1
        const float4 a = *(const float4*)(factors + (size_t)(2 * k    ) * 4);
        const float4 b = *(const float4*)(factors + (size_t)(2 * k + 1) * 4);
        c0 = stage0_apply(c0, a, b);
        c1 = stage0_apply(c1, a, b);
        c2 = stage0_apply(c2, a, b);
        c3 = stage0_apply(c3, a, b);
    }
#pragma unroll
    for (int s = 1; s < DEPTH; ++s) {
        const int lowmask = (1 << (s - 1)) - 1;
        const int p0 = ((k >> (s - 1)) << s) | (k & lowmask);
        const int p1 = p0 + (1 << (s - 1));
        const float4 a = *(const float4*)(factors + (size_t)(s * NPAIR + p0) * 4);
        const float4 b = *(const float4*)(factors + (size_t)(s * NPAIR + p1) * 4);
        c0 = stageS_apply(c0, a, b);
        c1 = stageS_apply(c1, a, b);
        c2 = stageS_apply(c2, a, b);
        c3 = stageS_apply(c3, a, b);
    }

    float4* m = (float4*)(M + (size_t)k * 16);
    m[0] = c0; m[1] = c1; m[2] = c2; m[3] = c3;
}

// ---- kernel 2: out[b] = M_k * x[b] + bias, pure stream ----
__global__ __launch_bounds__(GBLK)
void apply_kernel(const float* __restrict__ x,
                  const float* __restrict__ M,
                  const float* __restrict__ bias,
                  float* __restrict__ out)
{
    const int k    = blockIdx.x * GBLK + threadIdx.x;   // group 0..1023
    const int tok0 = blockIdx.y * TOK_PER_BLK;

    const float4* m = (const float4*)(M + (size_t)k * 16);
    const float4 c0 = m[0], c1 = m[1], c2 = m[2], c3 = m[3];
    const float4 bv = *(const float4*)(bias + 4 * k);

#pragma unroll
    for (int t = 0; t < TOK_PER_BLK; ++t) {
        const size_t off = (size_t)(tok0 + t) * NFEAT + 4 * k;
        const fx4 vv = __builtin_nontemporal_load((const fx4*)(x + off));
        fx4 r;
        r.x = bv.x + vv.x * c0.x + vv.y * c1.x + vv.z * c2.x + vv.w * c3.x;
        r.y = bv.y + vv.x * c0.y + vv.y * c1.y + vv.z * c2.y + vv.w * c3.y;
        r.z = bv.z + vv.x * c0.z + vv.y * c1.z + vv.z * c2.z + vv.w * c3.z;
        r.w = bv.w + vv.x * c0.w + vv.y * c1.w + vv.z * c2.w + vv.w * c3.w;
        __builtin_nontemporal_store(r, (fx4*)(out + off));
    }
}

extern "C" void kernel_launch(void* const* d_in, const int* in_sizes, int n_in,
                              void* d_out, int out_size, void* d_ws, size_t ws_size,
                              hipStream_t stream) {
    const float* x       = (const float*)d_in[0];
    const float* factors = (const float*)d_in[1];
    const float* bias    = (const float*)d_in[2];
    float* out           = (float*)d_out;
    float* M             = (float*)d_ws;    // 1024 * 16 floats = 64 KB

    compose_kernel<<<dim3(NGROUPS / 256), dim3(256), 0, stream>>>(factors, M);

    dim3 grid(NGROUPS / GBLK, TOKENS / TOK_PER_BLK);   // (4, 1024) = 4096 blocks
    apply_kernel<<<grid, dim3(GBLK), 0, stream>>>(x, M, bias, out);
}